// Round 1
// baseline (259.192 us; speedup 1.0000x reference)
//
#include <hip/hip_runtime.h>
#include <hip/hip_bf16.h>
#include <math.h>

#define BB 64
#define SS 2048
#define HH 512
#define VV 50257
#define KD 1024   // I + H
#define NSPLIT 32 // s-chunks per batch row

typedef float f32x4 __attribute__((ext_vector_type(4)));
typedef __bf16 bf16x8 __attribute__((ext_vector_type(8)));

__device__ __forceinline__ float dot4(float4 a, float4 b) {
  return a.x*b.x + a.y*b.y + a.z*b.z + a.w*b.w;
}

__device__ __forceinline__ bf16x8 cvt8(float4 a, float4 b) {
  bf16x8 r;
  r[0]=(__bf16)a.x; r[1]=(__bf16)a.y; r[2]=(__bf16)a.z; r[3]=(__bf16)a.w;
  r[4]=(__bf16)b.x; r[5]=(__bf16)b.y; r[6]=(__bf16)b.z; r[7]=(__bf16)b.w;
  return r;
}

// ---------------------------------------------------------------------------
// Kernel A: fused scores+softmax+context partials (online softmax).
// grid = BB*NSPLIT blocks, 256 threads (4 waves). Each wave handles 16 s.
// Lane l owns h-components [l*8, l*8+8). One pass over encoder_outputs.
// ---------------------------------------------------------------------------
__global__ __launch_bounds__(256) void attn_partial(
    const float* __restrict__ hprev, const float* __restrict__ enc,
    float* __restrict__ pm, float* __restrict__ pl, float* __restrict__ pacc)
{
  const int b = blockIdx.x >> 5;
  const int split = blockIdx.x & 31;
  const int t = threadIdx.x;
  const int w = t >> 6, lane = t & 63;

  const float* hb = hprev + b*HH + lane*8;
  const float4 h0 = *(const float4*)hb;
  const float4 h1 = *(const float4*)(hb + 4);

  float m = -INFINITY, lsum = 0.f;
  float acc[8];
#pragma unroll
  for (int j = 0; j < 8; ++j) acc[j] = 0.f;

  const int s0 = split*64 + w*16;
  for (int i = 0; i < 16; ++i) {
    const float* ep = enc + ((size_t)(s0 + i)*BB + b)*HH + lane*8;
    const float4 e0 = *(const float4*)ep;
    const float4 e1 = *(const float4*)(ep + 4);
    float d = dot4(h0, e0) + dot4(h1, e1);
#pragma unroll
    for (int off = 32; off >= 1; off >>= 1) d += __shfl_xor(d, off, 64);
    const float mn = fmaxf(m, d);
    const float sc = __expf(m - mn);   // first iter: exp(-inf)=0
    const float p  = __expf(d - mn);
    lsum = lsum*sc + p;
    acc[0]=acc[0]*sc+p*e0.x; acc[1]=acc[1]*sc+p*e0.y;
    acc[2]=acc[2]*sc+p*e0.z; acc[3]=acc[3]*sc+p*e0.w;
    acc[4]=acc[4]*sc+p*e1.x; acc[5]=acc[5]*sc+p*e1.y;
    acc[6]=acc[6]*sc+p*e1.z; acc[7]=acc[7]*sc+p*e1.w;
    m = mn;
  }

  // combine 4 waves of the block
  __shared__ float sm4[4], sl4[4];
  __shared__ float sacc[4][HH];
  if (lane == 0) { sm4[w] = m; sl4[w] = lsum; }
  __syncthreads();
  const float M = fmaxf(fmaxf(sm4[0], sm4[1]), fmaxf(sm4[2], sm4[3]));
  const float ew = __expf(m - M);      // wave-uniform
#pragma unroll
  for (int j = 0; j < 8; ++j) sacc[w][lane*8 + j] = acc[j]*ew;
  __syncthreads();

  const int rec = blockIdx.x;          // == b*NSPLIT + split
  for (int hh = t; hh < HH; hh += 256)
    pacc[(size_t)rec*HH + hh] = sacc[0][hh]+sacc[1][hh]+sacc[2][hh]+sacc[3][hh];
  if (t == 0) {
    float L = sl4[0]*__expf(sm4[0]-M) + sl4[1]*__expf(sm4[1]-M)
            + sl4[2]*__expf(sm4[2]-M) + sl4[3]*__expf(sm4[3]-M);
    pm[rec] = M; pl[rec] = L;
  }
}

// ---------------------------------------------------------------------------
// Kernel B: combine NSPLIT partials per b -> context -> feat[b][512..1024)
// ---------------------------------------------------------------------------
__global__ __launch_bounds__(256) void attn_reduce(
    const float* __restrict__ pm, const float* __restrict__ pl,
    const float* __restrict__ pacc, float* __restrict__ feat)
{
  const int b = blockIdx.x, t = threadIdx.x;
  __shared__ float smm[NSPLIT], sll[NSPLIT], sco[NSPLIT];
  if (t < NSPLIT) { smm[t] = pm[b*NSPLIT + t]; sll[t] = pl[b*NSPLIT + t]; }
  __syncthreads();
  float M = -INFINITY;
  for (int q = 0; q < NSPLIT; ++q) M = fmaxf(M, smm[q]);
  float L = 0.f;
  for (int q = 0; q < NSPLIT; ++q) L += sll[q]*__expf(smm[q]-M);
  const float inv = 1.f/L;
  if (t < NSPLIT) sco[t] = __expf(smm[t]-M)*inv;
  __syncthreads();
  for (int hh = t; hh < HH; hh += 256) {
    float s = 0.f;
    for (int q = 0; q < NSPLIT; ++q)
      s += pacc[((size_t)b*NSPLIT + q)*HH + hh]*sco[q];
    feat[b*KD + HH + hh] = s;
  }
}

// ---------------------------------------------------------------------------
// Kernel C: GRU step. One wave per (b, j). 6 dot products combined into 4
// butterfly reductions. Writes h_new to feat[b][j] and hidden output.
// grid = 512*16 (j fastest within XCD -> W-row reuse across b-groups).
// ---------------------------------------------------------------------------
__global__ __launch_bounds__(256) void gru_step(
    const int* __restrict__ last_out, const float* __restrict__ emb,
    const float* __restrict__ hprev,
    const float* __restrict__ W_ih, const float* __restrict__ b_ih,
    const float* __restrict__ W_hh, const float* __restrict__ b_hh,
    float* __restrict__ feat, float* __restrict__ hid_out)
{
  const int j = blockIdx.x >> 4;
  const int bg = blockIdx.x & 15;
  const int w = threadIdx.x >> 6, lane = threadIdx.x & 63;
  const int b = bg*4 + w;
  const size_t erow = (size_t)last_out[b] * HH;
  const int l4 = lane*4;

  // rnn_in[b][k]: k<512 -> embedding row; k>=512 -> context (feat[b][512+..])
  const float4 x0 = *(const float4*)(emb + erow + l4);
  const float4 x1 = *(const float4*)(emb + erow + 256 + l4);
  const float4 x2 = *(const float4*)(feat + (size_t)b*KD + 512 + l4);
  const float4 x3 = *(const float4*)(feat + (size_t)b*KD + 768 + l4);
  const float4 g0 = *(const float4*)(hprev + b*HH + l4);
  const float4 g1 = *(const float4*)(hprev + b*HH + 256 + l4);

  const float* wr = W_ih + (size_t)j*KD;
  const float* wz = W_ih + (size_t)(HH + j)*KD;
  const float* wn = W_ih + (size_t)(2*HH + j)*KD;
  const float* ur = W_hh + (size_t)j*HH;
  const float* uz = W_hh + (size_t)(HH + j)*HH;
  const float* un = W_hh + (size_t)(2*HH + j)*HH;

  float s_r = dot4(x0, *(const float4*)(wr + l4))
            + dot4(x1, *(const float4*)(wr + 256 + l4))
            + dot4(x2, *(const float4*)(wr + 512 + l4))
            + dot4(x3, *(const float4*)(wr + 768 + l4))
            + dot4(g0, *(const float4*)(ur + l4))
            + dot4(g1, *(const float4*)(ur + 256 + l4));
  float s_z = dot4(x0, *(const float4*)(wz + l4))
            + dot4(x1, *(const float4*)(wz + 256 + l4))
            + dot4(x2, *(const float4*)(wz + 512 + l4))
            + dot4(x3, *(const float4*)(wz + 768 + l4))
            + dot4(g0, *(const float4*)(uz + l4))
            + dot4(g1, *(const float4*)(uz + 256 + l4));
  float s_gn = dot4(x0, *(const float4*)(wn + l4))
             + dot4(x1, *(const float4*)(wn + 256 + l4))
             + dot4(x2, *(const float4*)(wn + 512 + l4))
             + dot4(x3, *(const float4*)(wn + 768 + l4));
  float s_hn = dot4(g0, *(const float4*)(un + l4))
             + dot4(g1, *(const float4*)(un + 256 + l4));

#pragma unroll
  for (int off = 32; off >= 1; off >>= 1) {
    s_r  += __shfl_xor(s_r,  off, 64);
    s_z  += __shfl_xor(s_z,  off, 64);
    s_gn += __shfl_xor(s_gn, off, 64);
    s_hn += __shfl_xor(s_hn, off, 64);
  }

  if (lane == 0) {
    const float r = 1.f/(1.f + __expf(-(s_r + b_ih[j] + b_hh[j])));
    const float z = 1.f/(1.f + __expf(-(s_z + b_ih[HH+j] + b_hh[HH+j])));
    const float n = tanhf(s_gn + b_ih[2*HH+j] + r*(s_hn + b_hh[2*HH+j]));
    const float hp = hprev[b*HH + j];
    const float hn = (1.f - z)*n + z*hp;
    feat[(size_t)b*KD + j] = hn;
    hid_out[b*HH + j] = hn;
  }
}

// ---------------------------------------------------------------------------
// Kernel D: logits = feat @ W_out^T + b_out via bf16 MFMA (in-register cvt).
// Block = 4 waves, each wave: 16 v-cols x 64 b-rows, K=1024 in steps of 32.
// A and B fragments use the SAME k-bijection -> layout-permutation safe.
// HBM-bound on W_out (206 MB read once).
// ---------------------------------------------------------------------------
__global__ __launch_bounds__(256) void logits_gemm(
    const float* __restrict__ feat, const float* __restrict__ W_out,
    const float* __restrict__ b_out, float* __restrict__ out)
{
  const int w = threadIdx.x >> 6, lane = threadIdx.x & 63;
  const int col = lane & 15, kg = lane >> 4;
  const int vbase = blockIdx.x*64 + w*16;
  const int v = vbase + col;
  const int vc = (v < VV) ? v : (VV - 1);

  const float* wp = W_out + (size_t)vc*KD + kg*8;
  f32x4 acc[4];
#pragma unroll
  for (int mt = 0; mt < 4; ++mt) acc[mt] = (f32x4){0.f,0.f,0.f,0.f};

  for (int k0 = 0; k0 < KD; k0 += 32) {
    const float4 wv0 = *(const float4*)(wp + k0);
    const float4 wv1 = *(const float4*)(wp + k0 + 4);
    const bf16x8 bf = cvt8(wv0, wv1);
#pragma unroll
    for (int mt = 0; mt < 4; ++mt) {
      const float* ap = feat + (size_t)(mt*16 + col)*KD + k0 + kg*8;
      const float4 a0 = *(const float4*)ap;
      const float4 a1 = *(const float4*)(ap + 4);
      const bf16x8 af = cvt8(a0, a1);
      acc[mt] = __builtin_amdgcn_mfma_f32_16x16x32_bf16(af, bf, acc[mt], 0, 0, 0);
    }
  }

  if (v < VV) {
    const float bo = b_out[v];
#pragma unroll
    for (int mt = 0; mt < 4; ++mt) {
#pragma unroll
      for (int reg = 0; reg < 4; ++reg) {
        const int brow = mt*16 + kg*4 + reg;   // verified C/D mapping
        out[(size_t)brow*VV + v] = acc[mt][reg] + bo;
      }
    }
  }
}

// ---------------------------------------------------------------------------
// Kernel E: in-place log_softmax over each row of logits.
// ---------------------------------------------------------------------------
__global__ __launch_bounds__(1024) void log_softmax_k(float* __restrict__ out)
{
  const int b = blockIdx.x, t = threadIdx.x;
  const int wid = t >> 6, lane = t & 63;
  float* p = out + (size_t)b*VV;
  __shared__ float red[16];

  float m = -INFINITY;
  for (int i = t; i < VV; i += 1024) m = fmaxf(m, p[i]);
#pragma unroll
  for (int off = 32; off >= 1; off >>= 1) m = fmaxf(m, __shfl_xor(m, off, 64));
  if (lane == 0) red[wid] = m;
  __syncthreads();
  float M = -INFINITY;
  for (int q = 0; q < 16; ++q) M = fmaxf(M, red[q]);
  __syncthreads();

  float s = 0.f;
  for (int i = t; i < VV; i += 1024) s += __expf(p[i] - M);
#pragma unroll
  for (int off = 32; off >= 1; off >>= 1) s += __shfl_xor(s, off, 64);
  if (lane == 0) red[wid] = s;
  __syncthreads();
  float S = 0.f;
  for (int q = 0; q < 16; ++q) S += red[q];
  const float c = M + logf(S);

  for (int i = t; i < VV; i += 1024) p[i] -= c;
}

// ---------------------------------------------------------------------------
extern "C" void kernel_launch(void* const* d_in, const int* in_sizes, int n_in,
                              void* d_out, int out_size, void* d_ws, size_t ws_size,
                              hipStream_t stream)
{
  const int*   last_output = (const int*)d_in[0];
  const float* last_hidden = (const float*)d_in[1];   // (1,B,H) -> h_top
  const float* enc         = (const float*)d_in[2];
  const float* emb         = (const float*)d_in[3];
  const float* W_ih        = (const float*)d_in[4];
  const float* b_ih        = (const float*)d_in[5];
  const float* W_hh        = (const float*)d_in[6];
  const float* b_hh        = (const float*)d_in[7];
  const float* W_out       = (const float*)d_in[8];
  const float* b_out       = (const float*)d_in[9];
  float* out = (float*)d_out;

  // ws: feat (64x1024) + pm (2048) + pl (2048)  = ~280 KB
  float* feat = (float*)d_ws;
  float* pm   = feat + (size_t)BB*KD;
  float* pl   = pm + BB*NSPLIT;
  // big partial-acc scratch (4 MB) parked in the (not-yet-written) logits area
  float* pacc = out;

  float* logits  = out;
  float* hid_out = out + (size_t)BB*VV;

  attn_partial<<<dim3(BB*NSPLIT), dim3(256), 0, stream>>>(last_hidden, enc, pm, pl, pacc);
  attn_reduce <<<dim3(BB),        dim3(256), 0, stream>>>(pm, pl, pacc, feat);
  gru_step    <<<dim3(512*16),    dim3(256), 0, stream>>>(last_output, emb, last_hidden,
                                                          W_ih, b_ih, W_hh, b_hh,
                                                          feat, hid_out);
  logits_gemm <<<dim3((VV + 63)/64), dim3(256), 0, stream>>>(feat, W_out, b_out, logits);
  log_softmax_k<<<dim3(BB), dim3(1024), 0, stream>>>(logits);
}

// Round 2
// 253.837 us; speedup vs baseline: 1.0211x; 1.0211x over previous
//
#include <hip/hip_runtime.h>
#include <hip/hip_bf16.h>
#include <math.h>

#define BB 64
#define SS 2048
#define HH 512
#define VV 50257
#define KD 1024   // I + H
#define NSPLIT 32 // s-chunks per batch row
#define LCH 8     // log-softmax chunks per row
#define LCHW 6283 // ceil(VV/LCH)

typedef float f32x4 __attribute__((ext_vector_type(4)));
typedef __bf16 bf16x8 __attribute__((ext_vector_type(8)));

__device__ __forceinline__ float dot4(float4 a, float4 b) {
  return a.x*b.x + a.y*b.y + a.z*b.z + a.w*b.w;
}

__device__ __forceinline__ bf16x8 cvt8(float4 a, float4 b) {
  bf16x8 r;
  r[0]=(__bf16)a.x; r[1]=(__bf16)a.y; r[2]=(__bf16)a.z; r[3]=(__bf16)a.w;
  r[4]=(__bf16)b.x; r[5]=(__bf16)b.y; r[6]=(__bf16)b.z; r[7]=(__bf16)b.w;
  return r;
}

// ---------------------------------------------------------------------------
// Kernel A: fused scores+softmax+context partials (online softmax).
// ---------------------------------------------------------------------------
__global__ __launch_bounds__(256) void attn_partial(
    const float* __restrict__ hprev, const float* __restrict__ enc,
    float* __restrict__ pm, float* __restrict__ pl, float* __restrict__ pacc)
{
  const int b = blockIdx.x >> 5;
  const int split = blockIdx.x & 31;
  const int t = threadIdx.x;
  const int w = t >> 6, lane = t & 63;

  const float* hb = hprev + b*HH + lane*8;
  const float4 h0 = *(const float4*)hb;
  const float4 h1 = *(const float4*)(hb + 4);

  float m = -INFINITY, lsum = 0.f;
  float acc[8];
#pragma unroll
  for (int j = 0; j < 8; ++j) acc[j] = 0.f;

  const int s0 = split*64 + w*16;
  for (int i = 0; i < 16; ++i) {
    const float* ep = enc + ((size_t)(s0 + i)*BB + b)*HH + lane*8;
    const float4 e0 = *(const float4*)ep;
    const float4 e1 = *(const float4*)(ep + 4);
    float d = dot4(h0, e0) + dot4(h1, e1);
#pragma unroll
    for (int off = 32; off >= 1; off >>= 1) d += __shfl_xor(d, off, 64);
    const float mn = fmaxf(m, d);
    const float sc = __expf(m - mn);
    const float p  = __expf(d - mn);
    lsum = lsum*sc + p;
    acc[0]=acc[0]*sc+p*e0.x; acc[1]=acc[1]*sc+p*e0.y;
    acc[2]=acc[2]*sc+p*e0.z; acc[3]=acc[3]*sc+p*e0.w;
    acc[4]=acc[4]*sc+p*e1.x; acc[5]=acc[5]*sc+p*e1.y;
    acc[6]=acc[6]*sc+p*e1.z; acc[7]=acc[7]*sc+p*e1.w;
    m = mn;
  }

  __shared__ float sm4[4], sl4[4];
  __shared__ float sacc[4][HH];
  if (lane == 0) { sm4[w] = m; sl4[w] = lsum; }
  __syncthreads();
  const float M = fmaxf(fmaxf(sm4[0], sm4[1]), fmaxf(sm4[2], sm4[3]));
  const float ew = __expf(m - M);
#pragma unroll
  for (int j = 0; j < 8; ++j) sacc[w][lane*8 + j] = acc[j]*ew;
  __syncthreads();

  const int rec = blockIdx.x;
  for (int hh = t; hh < HH; hh += 256)
    pacc[(size_t)rec*HH + hh] = sacc[0][hh]+sacc[1][hh]+sacc[2][hh]+sacc[3][hh];
  if (t == 0) {
    float L = sl4[0]*__expf(sm4[0]-M) + sl4[1]*__expf(sm4[1]-M)
            + sl4[2]*__expf(sm4[2]-M) + sl4[3]*__expf(sm4[3]-M);
    pm[rec] = M; pl[rec] = L;
  }
}

// ---------------------------------------------------------------------------
// Kernel B: combine NSPLIT partials per b -> context -> feat[b][512..1024)
// ---------------------------------------------------------------------------
__global__ __launch_bounds__(256) void attn_reduce(
    const float* __restrict__ pm, const float* __restrict__ pl,
    const float* __restrict__ pacc, float* __restrict__ feat)
{
  const int b = blockIdx.x, t = threadIdx.x;
  __shared__ float smm[NSPLIT], sll[NSPLIT], sco[NSPLIT];
  if (t < NSPLIT) { smm[t] = pm[b*NSPLIT + t]; sll[t] = pl[b*NSPLIT + t]; }
  __syncthreads();
  float M = -INFINITY;
  for (int q = 0; q < NSPLIT; ++q) M = fmaxf(M, smm[q]);
  float L = 0.f;
  for (int q = 0; q < NSPLIT; ++q) L += sll[q]*__expf(smm[q]-M);
  const float inv = 1.f/L;
  if (t < NSPLIT) sco[t] = __expf(smm[t]-M)*inv;
  __syncthreads();
  for (int hh = t; hh < HH; hh += 256) {
    float s = 0.f;
    for (int q = 0; q < NSPLIT; ++q)
      s += pacc[((size_t)b*NSPLIT + q)*HH + hh]*sco[q];
    feat[b*KD + HH + hh] = s;
  }
}

// ---------------------------------------------------------------------------
// Kernel C: GRU step. One wave per (b, j). XCD-swizzled so all 16 blocks
// sharing a weight row j land on the same XCD (bid % 8 constant per j)
// -> per-XCD weight working set 9.4MB/8 = 1.2MB, L2-resident.
// ---------------------------------------------------------------------------
__global__ __launch_bounds__(256) void gru_step(
    const int* __restrict__ last_out, const float* __restrict__ emb,
    const float* __restrict__ hprev,
    const float* __restrict__ W_ih, const float* __restrict__ b_ih,
    const float* __restrict__ W_hh, const float* __restrict__ b_hh,
    float* __restrict__ feat, float* __restrict__ hid_out)
{
  const int bid = blockIdx.x;
  const int j  = (bid & 7) + ((bid >> 7) << 3);  // same j -> same bid%8 (XCD)
  const int bg = (bid >> 3) & 15;
  const int w = threadIdx.x >> 6, lane = threadIdx.x & 63;
  const int b = bg*4 + w;
  const size_t erow = (size_t)last_out[b] * HH;
  const int l4 = lane*4;

  const float4 x0 = *(const float4*)(emb + erow + l4);
  const float4 x1 = *(const float4*)(emb + erow + 256 + l4);
  const float4 x2 = *(const float4*)(feat + (size_t)b*KD + 512 + l4);
  const float4 x3 = *(const float4*)(feat + (size_t)b*KD + 768 + l4);
  const float4 g0 = *(const float4*)(hprev + b*HH + l4);
  const float4 g1 = *(const float4*)(hprev + b*HH + 256 + l4);

  const float* wr = W_ih + (size_t)j*KD;
  const float* wz = W_ih + (size_t)(HH + j)*KD;
  const float* wn = W_ih + (size_t)(2*HH + j)*KD;
  const float* ur = W_hh + (size_t)j*HH;
  const float* uz = W_hh + (size_t)(HH + j)*HH;
  const float* un = W_hh + (size_t)(2*HH + j)*HH;

  float s_r = dot4(x0, *(const float4*)(wr + l4))
            + dot4(x1, *(const float4*)(wr + 256 + l4))
            + dot4(x2, *(const float4*)(wr + 512 + l4))
            + dot4(x3, *(const float4*)(wr + 768 + l4))
            + dot4(g0, *(const float4*)(ur + l4))
            + dot4(g1, *(const float4*)(ur + 256 + l4));
  float s_z = dot4(x0, *(const float4*)(wz + l4))
            + dot4(x1, *(const float4*)(wz + 256 + l4))
            + dot4(x2, *(const float4*)(wz + 512 + l4))
            + dot4(x3, *(const float4*)(wz + 768 + l4))
            + dot4(g0, *(const float4*)(uz + l4))
            + dot4(g1, *(const float4*)(uz + 256 + l4));
  float s_gn = dot4(x0, *(const float4*)(wn + l4))
             + dot4(x1, *(const float4*)(wn + 256 + l4))
             + dot4(x2, *(const float4*)(wn + 512 + l4))
             + dot4(x3, *(const float4*)(wn + 768 + l4));
  float s_hn = dot4(g0, *(const float4*)(un + l4))
             + dot4(g1, *(const float4*)(un + 256 + l4));

#pragma unroll
  for (int off = 32; off >= 1; off >>= 1) {
    s_r  += __shfl_xor(s_r,  off, 64);
    s_z  += __shfl_xor(s_z,  off, 64);
    s_gn += __shfl_xor(s_gn, off, 64);
    s_hn += __shfl_xor(s_hn, off, 64);
  }

  if (lane == 0) {
    const float r = 1.f/(1.f + __expf(-(s_r + b_ih[j] + b_hh[j])));
    const float z = 1.f/(1.f + __expf(-(s_z + b_ih[HH+j] + b_hh[HH+j])));
    const float n = tanhf(s_gn + b_ih[2*HH+j] + r*(s_hn + b_hh[2*HH+j]));
    const float hp = hprev[b*HH + j];
    const float hn = (1.f - z)*n + z*hp;
    feat[(size_t)b*KD + j] = hn;
    hid_out[b*HH + j] = hn;
  }
}

// ---------------------------------------------------------------------------
// Kernel D: logits = feat @ W_out^T + b_out via bf16 MFMA (in-register cvt).
// ---------------------------------------------------------------------------
__global__ __launch_bounds__(256) void logits_gemm(
    const float* __restrict__ feat, const float* __restrict__ W_out,
    const float* __restrict__ b_out, float* __restrict__ out)
{
  const int w = threadIdx.x >> 6, lane = threadIdx.x & 63;
  const int col = lane & 15, kg = lane >> 4;
  const int vbase = blockIdx.x*64 + w*16;
  const int v = vbase + col;
  const int vc = (v < VV) ? v : (VV - 1);

  const float* wp = W_out + (size_t)vc*KD + kg*8;
  f32x4 acc[4];
#pragma unroll
  for (int mt = 0; mt < 4; ++mt) acc[mt] = (f32x4){0.f,0.f,0.f,0.f};

#pragma unroll 2
  for (int k0 = 0; k0 < KD; k0 += 32) {
    const float4 wv0 = *(const float4*)(wp + k0);
    const float4 wv1 = *(const float4*)(wp + k0 + 4);
    const bf16x8 bf = cvt8(wv0, wv1);
#pragma unroll
    for (int mt = 0; mt < 4; ++mt) {
      const float* ap = feat + (size_t)(mt*16 + col)*KD + k0 + kg*8;
      const float4 a0 = *(const float4*)ap;
      const float4 a1 = *(const float4*)(ap + 4);
      const bf16x8 af = cvt8(a0, a1);
      acc[mt] = __builtin_amdgcn_mfma_f32_16x16x32_bf16(af, bf, acc[mt], 0, 0, 0);
    }
  }

  if (v < VV) {
    const float bo = b_out[v];
#pragma unroll
    for (int mt = 0; mt < 4; ++mt) {
#pragma unroll
      for (int reg = 0; reg < 4; ++reg) {
        const int brow = mt*16 + kg*4 + reg;
        out[(size_t)brow*VV + v] = acc[mt][reg] + bo;
      }
    }
  }
}

// ---------------------------------------------------------------------------
// Kernel E1: per-(row,chunk) online max/expsum partials. grid = BB*LCH.
// ---------------------------------------------------------------------------
__global__ __launch_bounds__(256) void lsm_partial(
    const float* __restrict__ out, float* __restrict__ pm2, float* __restrict__ pl2)
{
  const int b = blockIdx.x >> 3, ch = blockIdx.x & (LCH-1);
  const int t = threadIdx.x;
  const int beg = ch*LCHW;
  const int end = (beg + LCHW < VV) ? beg + LCHW : VV;
  const float* p = out + (size_t)b*VV;

  float m = -INFINITY, l = 0.f;
  for (int i = beg + t; i < end; i += 256) {
    const float v = p[i];
    const float mn = fmaxf(m, v);
    l = l*__expf(m - mn) + __expf(v - mn);
    m = mn;
  }
#pragma unroll
  for (int off = 32; off >= 1; off >>= 1) {
    const float m2 = __shfl_xor(m, off, 64), l2 = __shfl_xor(l, off, 64);
    const float mn = fmaxf(m, m2);
    l = l*__expf(m - mn) + l2*__expf(m2 - mn);
    m = mn;
  }
  __shared__ float sm[4], sl[4];
  const int w = t >> 6, lane = t & 63;
  if (lane == 0) { sm[w] = m; sl[w] = l; }
  __syncthreads();
  if (t == 0) {
    float M = sm[0], L = sl[0];
    for (int q = 1; q < 4; ++q) {
      const float mn = fmaxf(M, sm[q]);
      L = L*__expf(M - mn) + sl[q]*__expf(sm[q] - mn);
      M = mn;
    }
    pm2[blockIdx.x] = M; pl2[blockIdx.x] = L;
  }
}

// ---------------------------------------------------------------------------
// Kernel E2: combine LCH partials per row -> c[b] = M + log(L). 1 block.
// ---------------------------------------------------------------------------
__global__ __launch_bounds__(64) void lsm_reduce(
    const float* __restrict__ pm2, const float* __restrict__ pl2,
    float* __restrict__ c)
{
  const int b = threadIdx.x;
  float M = -INFINITY, L = 0.f;
#pragma unroll
  for (int q = 0; q < LCH; ++q) {
    const float m = pm2[b*LCH + q], l = pl2[b*LCH + q];
    const float mn = fmaxf(M, m);
    L = L*__expf(M - mn) + l*__expf(m - mn);
    M = mn;
  }
  c[b] = M + logf(L);
}

// ---------------------------------------------------------------------------
// Kernel E3: logits -= c[row], vectorized float4 over the flat array.
// ---------------------------------------------------------------------------
__global__ __launch_bounds__(256) void lsm_sub(
    float* __restrict__ out, const float* __restrict__ c)
{
  const unsigned idx4 = blockIdx.x*256u + threadIdx.x;
  const unsigned i = idx4*4u;
  if (i >= (unsigned)BB*VV) return;
  float4 v = *(float4*)(out + i);
  const int b0 = i / VV, b1 = (i + 3) / VV;
  if (b0 == b1) {
    const float cc = c[b0];
    v.x -= cc; v.y -= cc; v.z -= cc; v.w -= cc;
  } else {
    v.x -= c[(i)     / VV];
    v.y -= c[(i + 1) / VV];
    v.z -= c[(i + 2) / VV];
    v.w -= c[(i + 3) / VV];
  }
  *(float4*)(out + i) = v;
}

// ---------------------------------------------------------------------------
extern "C" void kernel_launch(void* const* d_in, const int* in_sizes, int n_in,
                              void* d_out, int out_size, void* d_ws, size_t ws_size,
                              hipStream_t stream)
{
  const int*   last_output = (const int*)d_in[0];
  const float* last_hidden = (const float*)d_in[1];
  const float* enc         = (const float*)d_in[2];
  const float* emb         = (const float*)d_in[3];
  const float* W_ih        = (const float*)d_in[4];
  const float* b_ih        = (const float*)d_in[5];
  const float* W_hh        = (const float*)d_in[6];
  const float* b_hh        = (const float*)d_in[7];
  const float* W_out       = (const float*)d_in[8];
  const float* b_out       = (const float*)d_in[9];
  float* out = (float*)d_out;

  float* feat = (float*)d_ws;                       // 64x1024
  float* pm   = feat + (size_t)BB*KD;               // 2048
  float* pl   = pm + BB*NSPLIT;                     // 2048
  float* pm2  = pl + BB*NSPLIT;                     // 512
  float* pl2  = pm2 + BB*LCH;                       // 512
  float* cc   = pl2 + BB*LCH;                       // 64
  float* pacc = out;                                // 4MB parked in dead logits

  float* logits  = out;
  float* hid_out = out + (size_t)BB*VV;

  attn_partial<<<dim3(BB*NSPLIT), dim3(256), 0, stream>>>(last_hidden, enc, pm, pl, pacc);
  attn_reduce <<<dim3(BB),        dim3(256), 0, stream>>>(pm, pl, pacc, feat);
  gru_step    <<<dim3(512*16),    dim3(256), 0, stream>>>(last_output, emb, last_hidden,
                                                          W_ih, b_ih, W_hh, b_hh,
                                                          feat, hid_out);
  logits_gemm <<<dim3((VV + 63)/64), dim3(256), 0, stream>>>(feat, W_out, b_out, logits);
  lsm_partial <<<dim3(BB*LCH), dim3(256), 0, stream>>>(logits, pm2, pl2);
  lsm_reduce  <<<dim3(1), dim3(64), 0, stream>>>(pm2, pl2, cc);
  lsm_sub     <<<dim3((BB*VV/4 + 255)/256), dim3(256), 0, stream>>>(logits, cc);
}

// Round 3
// 213.442 us; speedup vs baseline: 1.2143x; 1.1893x over previous
//
#include <hip/hip_runtime.h>
#include <hip/hip_bf16.h>
#include <math.h>

#define BB 64
#define SS 2048
#define HH 512
#define VV 50257
#define KD 1024   // I + H
#define NSPLIT 32 // attn s-chunks per batch row
#define LCH 8     // log-softmax chunks per row
#define LPT 25    // elems per thread in lsm_partial (256*25=6400/chunk)

typedef float f32x4 __attribute__((ext_vector_type(4)));
typedef __bf16 bf16x8 __attribute__((ext_vector_type(8)));

__device__ __forceinline__ float dot4(float4 a, float4 b) {
  return a.x*b.x + a.y*b.y + a.z*b.z + a.w*b.w;
}

__device__ __forceinline__ bf16x8 cvt8(float4 a, float4 b) {
  bf16x8 r;
  r[0]=(__bf16)a.x; r[1]=(__bf16)a.y; r[2]=(__bf16)a.z; r[3]=(__bf16)a.w;
  r[4]=(__bf16)b.x; r[5]=(__bf16)b.y; r[6]=(__bf16)b.z; r[7]=(__bf16)b.w;
  return r;
}

// ---------------------------------------------------------------------------
// Kernel A: fused scores+softmax+context partials. Online softmax with ONE
// rescale per group of 4 s (group-max trick) -> 4x shorter serial chain,
// 4 butterfly reduces pipeline together.
// ---------------------------------------------------------------------------
__global__ __launch_bounds__(256) void attn_partial(
    const float* __restrict__ hprev, const float* __restrict__ enc,
    float* __restrict__ pm, float* __restrict__ pl, float* __restrict__ pacc)
{
  const int b = blockIdx.x >> 5;
  const int split = blockIdx.x & 31;
  const int t = threadIdx.x;
  const int w = t >> 6, lane = t & 63;

  const float* hb = hprev + b*HH + lane*8;
  const float4 h0 = *(const float4*)hb;
  const float4 h1 = *(const float4*)(hb + 4);

  float m = -INFINITY, lsum = 0.f;
  float acc[8];
#pragma unroll
  for (int j = 0; j < 8; ++j) acc[j] = 0.f;

  const int s0 = split*64 + w*16;
#pragma unroll
  for (int g = 0; g < 4; ++g) {
    const float* ep0 = enc + ((size_t)(s0 + g*4 + 0)*BB + b)*HH + lane*8;
    const float* ep1 = enc + ((size_t)(s0 + g*4 + 1)*BB + b)*HH + lane*8;
    const float* ep2 = enc + ((size_t)(s0 + g*4 + 2)*BB + b)*HH + lane*8;
    const float* ep3 = enc + ((size_t)(s0 + g*4 + 3)*BB + b)*HH + lane*8;
    const float4 e0a = *(const float4*)ep0, e0b = *(const float4*)(ep0+4);
    const float4 e1a = *(const float4*)ep1, e1b = *(const float4*)(ep1+4);
    const float4 e2a = *(const float4*)ep2, e2b = *(const float4*)(ep2+4);
    const float4 e3a = *(const float4*)ep3, e3b = *(const float4*)(ep3+4);

    float d0 = dot4(h0,e0a) + dot4(h1,e0b);
    float d1 = dot4(h0,e1a) + dot4(h1,e1b);
    float d2 = dot4(h0,e2a) + dot4(h1,e2b);
    float d3 = dot4(h0,e3a) + dot4(h1,e3b);
#pragma unroll
    for (int off = 32; off >= 1; off >>= 1) {
      d0 += __shfl_xor(d0, off, 64);
      d1 += __shfl_xor(d1, off, 64);
      d2 += __shfl_xor(d2, off, 64);
      d3 += __shfl_xor(d3, off, 64);
    }
    const float gm = fmaxf(fmaxf(d0,d1), fmaxf(d2,d3));
    const float mn = fmaxf(m, gm);
    const float sc = __expf(m - mn);     // first group: exp(-inf)=0
    const float p0 = __expf(d0 - mn), p1 = __expf(d1 - mn);
    const float p2 = __expf(d2 - mn), p3 = __expf(d3 - mn);
    lsum = lsum*sc + ((p0+p1) + (p2+p3));
    acc[0] = acc[0]*sc + p0*e0a.x + p1*e1a.x + p2*e2a.x + p3*e3a.x;
    acc[1] = acc[1]*sc + p0*e0a.y + p1*e1a.y + p2*e2a.y + p3*e3a.y;
    acc[2] = acc[2]*sc + p0*e0a.z + p1*e1a.z + p2*e2a.z + p3*e3a.z;
    acc[3] = acc[3]*sc + p0*e0a.w + p1*e1a.w + p2*e2a.w + p3*e3a.w;
    acc[4] = acc[4]*sc + p0*e0b.x + p1*e1b.x + p2*e2b.x + p3*e3b.x;
    acc[5] = acc[5]*sc + p0*e0b.y + p1*e1b.y + p2*e2b.y + p3*e3b.y;
    acc[6] = acc[6]*sc + p0*e0b.z + p1*e1b.z + p2*e2b.z + p3*e3b.z;
    acc[7] = acc[7]*sc + p0*e0b.w + p1*e1b.w + p2*e2b.w + p3*e3b.w;
    m = mn;
  }

  __shared__ float sm4[4], sl4[4];
  __shared__ float sacc[4][HH];
  if (lane == 0) { sm4[w] = m; sl4[w] = lsum; }
  __syncthreads();
  const float M = fmaxf(fmaxf(sm4[0], sm4[1]), fmaxf(sm4[2], sm4[3]));
  const float ew = __expf(m - M);
#pragma unroll
  for (int j = 0; j < 8; ++j) sacc[w][lane*8 + j] = acc[j]*ew;
  __syncthreads();

  const int rec = blockIdx.x;
  for (int hh = t; hh < HH; hh += 256)
    pacc[(size_t)rec*HH + hh] = sacc[0][hh]+sacc[1][hh]+sacc[2][hh]+sacc[3][hh];
  if (t == 0) {
    float L = sl4[0]*__expf(sm4[0]-M) + sl4[1]*__expf(sm4[1]-M)
            + sl4[2]*__expf(sm4[2]-M) + sl4[3]*__expf(sm4[3]-M);
    pm[rec] = M; pl[rec] = L;
  }
}

// ---------------------------------------------------------------------------
// Kernel B: combine NSPLIT partials per b -> context (bf16) -> featb[b][512+..]
// ---------------------------------------------------------------------------
__global__ __launch_bounds__(256) void attn_reduce(
    const float* __restrict__ pm, const float* __restrict__ pl,
    const float* __restrict__ pacc, __hip_bfloat16* __restrict__ featb)
{
  const int b = blockIdx.x, t = threadIdx.x;
  __shared__ float smm[NSPLIT], sll[NSPLIT], sco[NSPLIT];
  if (t < NSPLIT) { smm[t] = pm[b*NSPLIT + t]; sll[t] = pl[b*NSPLIT + t]; }
  __syncthreads();
  float M = -INFINITY;
  for (int q = 0; q < NSPLIT; ++q) M = fmaxf(M, smm[q]);
  float L = 0.f;
  for (int q = 0; q < NSPLIT; ++q) L += sll[q]*__expf(smm[q]-M);
  const float inv = 1.f/L;
  if (t < NSPLIT) sco[t] = __expf(smm[t]-M)*inv;
  __syncthreads();
  for (int hh = t; hh < HH; hh += 256) {
    float s = 0.f;
    for (int q = 0; q < NSPLIT; ++q)
      s += pacc[((size_t)b*NSPLIT + q)*HH + hh]*sco[q];
    featb[b*KD + HH + hh] = (__hip_bfloat16)s;
  }
}

// ---------------------------------------------------------------------------
// Kernel C: GRU gates as MFMA GEMM. gates[b, g] over virtual K=1536 split in
// 3 source segments (emb-gather / context / hprev). grid = 24 gtiles x 3 seg.
// Weights read once total (9.4 MB). Partials to ws, summed in pointwise.
// ---------------------------------------------------------------------------
__global__ __launch_bounds__(256) void gru_gemm(
    const int* __restrict__ last_out, const float* __restrict__ emb,
    const float* __restrict__ hprev, const __hip_bfloat16* __restrict__ featb,
    const float* __restrict__ W_ih, const float* __restrict__ W_hh,
    float* __restrict__ gates)  // [3][BB][1536]
{
  const int gt  = blockIdx.x / 3;
  const int seg = blockIdx.x % 3;
  const int w = threadIdx.x >> 6, lane = threadIdx.x & 63;
  const int col = lane & 15, kg = lane >> 4;
  const int g = gt*64 + w*16 + col;

  // B-operand base: weight row g, 512-wide K window for this segment
  const float* wrow = (seg == 2) ? (W_hh + (size_t)g*HH)
                                 : (W_ih + (size_t)g*KD + seg*HH);

  // A-operand row indices (4 m-tiles of 16 b-rows; this lane covers b = mt*16+col)
  int lo_r[4];
#pragma unroll
  for (int mt = 0; mt < 4; ++mt) lo_r[mt] = last_out[mt*16 + col];

  f32x4 acc[4];
#pragma unroll
  for (int mt = 0; mt < 4; ++mt) acc[mt] = (f32x4){0.f,0.f,0.f,0.f};

  for (int k0 = 0; k0 < HH; k0 += 32) {
    const float* wp = wrow + k0 + kg*8;
    const bf16x8 bf = cvt8(*(const float4*)wp, *(const float4*)(wp+4));
#pragma unroll
    for (int mt = 0; mt < 4; ++mt) {
      const int bb = mt*16 + col;
      bf16x8 af;
      if (seg == 0) {
        const float* ap = emb + (size_t)lo_r[mt]*HH + k0 + kg*8;
        af = cvt8(*(const float4*)ap, *(const float4*)(ap+4));
      } else if (seg == 1) {
        af = *(const bf16x8*)(featb + (size_t)bb*KD + HH + k0 + kg*8);
      } else {
        const float* ap = hprev + (size_t)bb*HH + k0 + kg*8;
        af = cvt8(*(const float4*)ap, *(const float4*)(ap+4));
      }
      acc[mt] = __builtin_amdgcn_mfma_f32_16x16x32_bf16(af, bf, acc[mt], 0, 0, 0);
    }
  }

  float* gp = gates + (size_t)seg*BB*1536;
#pragma unroll
  for (int mt = 0; mt < 4; ++mt)
#pragma unroll
    for (int reg = 0; reg < 4; ++reg) {
      const int brow = mt*16 + kg*4 + reg;
      gp[(size_t)brow*1536 + g] = acc[mt][reg];
    }
}

// ---------------------------------------------------------------------------
// Kernel C2: GRU pointwise. r,z,n from gate partials -> h_new.
// ---------------------------------------------------------------------------
__global__ __launch_bounds__(512) void gru_pointwise(
    const float* __restrict__ gates, const float* __restrict__ hprev,
    const float* __restrict__ b_ih, const float* __restrict__ b_hh,
    float* __restrict__ hid_out, __hip_bfloat16* __restrict__ featb)
{
  const int b = blockIdx.x, j = threadIdx.x;
  const float* g0 = gates + (size_t)b*1536;            // seg0 (emb part of gi)
  const float* g1 = gates + (size_t)(BB + b)*1536;     // seg1 (ctx part of gi)
  const float* g2 = gates + (size_t)(2*BB + b)*1536;   // seg2 (gh)

  const float i_r = g0[j]        + g1[j];
  const float i_z = g0[HH + j]   + g1[HH + j];
  const float i_n = g0[2*HH + j] + g1[2*HH + j];
  const float h_r = g2[j];
  const float h_z = g2[HH + j];
  const float h_n = g2[2*HH + j];

  const float r = 1.f/(1.f + __expf(-(i_r + h_r + b_ih[j] + b_hh[j])));
  const float z = 1.f/(1.f + __expf(-(i_z + h_z + b_ih[HH+j] + b_hh[HH+j])));
  const float n = tanhf(i_n + b_ih[2*HH+j] + r*(h_n + b_hh[2*HH+j]));
  const float hp = hprev[b*HH + j];
  const float hn = (1.f - z)*n + z*hp;
  hid_out[b*HH + j] = hn;
  featb[(size_t)b*KD + j] = (__hip_bfloat16)hn;
}

// ---------------------------------------------------------------------------
// Kernel D: logits = featb @ W_out^T + b_out. A is pre-converted bf16.
// ---------------------------------------------------------------------------
__global__ __launch_bounds__(256) void logits_gemm(
    const __hip_bfloat16* __restrict__ featb, const float* __restrict__ W_out,
    const float* __restrict__ b_out, float* __restrict__ out)
{
  const int w = threadIdx.x >> 6, lane = threadIdx.x & 63;
  const int col = lane & 15, kg = lane >> 4;
  const int vbase = blockIdx.x*64 + w*16;
  const int v = vbase + col;
  const int vc = (v < VV) ? v : (VV - 1);

  const float* wp = W_out + (size_t)vc*KD + kg*8;
  f32x4 acc[4];
#pragma unroll
  for (int mt = 0; mt < 4; ++mt) acc[mt] = (f32x4){0.f,0.f,0.f,0.f};

#pragma unroll 4
  for (int k0 = 0; k0 < KD; k0 += 32) {
    const bf16x8 bf = cvt8(*(const float4*)(wp + k0), *(const float4*)(wp + k0 + 4));
#pragma unroll
    for (int mt = 0; mt < 4; ++mt) {
      const bf16x8 af = *(const bf16x8*)(featb + (size_t)(mt*16 + col)*KD + k0 + kg*8);
      acc[mt] = __builtin_amdgcn_mfma_f32_16x16x32_bf16(af, bf, acc[mt], 0, 0, 0);
    }
  }

  if (v < VV) {
    const float bo = b_out[v];
#pragma unroll
    for (int mt = 0; mt < 4; ++mt)
#pragma unroll
      for (int reg = 0; reg < 4; ++reg) {
        const int brow = mt*16 + kg*4 + reg;
        out[(size_t)brow*VV + v] = acc[mt][reg] + bo;
      }
  }
}

// ---------------------------------------------------------------------------
// Kernel E1: per-(row,chunk) max/expsum, two-pass in registers (1 exp/elem,
// no per-element serial rescale). grid = BB*LCH.
// ---------------------------------------------------------------------------
__global__ __launch_bounds__(256) void lsm_partial(
    const float* __restrict__ out, float* __restrict__ pm2, float* __restrict__ pl2)
{
  const int b = blockIdx.x >> 3, ch = blockIdx.x & (LCH-1);
  const int t = threadIdx.x;
  const float* p = out + (size_t)b*VV;
  const int beg = ch*(256*LPT);

  float r[LPT];
#pragma unroll
  for (int i = 0; i < LPT; ++i) {
    const int idx = beg + t + i*256;
    r[i] = (idx < VV) ? p[idx] : -INFINITY;
  }
  float m = r[0];
#pragma unroll
  for (int i = 1; i < LPT; ++i) m = fmaxf(m, r[i]);
  float l = 0.f;
#pragma unroll
  for (int i = 0; i < LPT; ++i) l += __expf(r[i] - m);

#pragma unroll
  for (int off = 32; off >= 1; off >>= 1) {
    const float m2 = __shfl_xor(m, off, 64), l2 = __shfl_xor(l, off, 64);
    const float mn = fmaxf(m, m2);
    l = l*__expf(m - mn) + l2*__expf(m2 - mn);
    m = mn;
  }
  __shared__ float sm[4], sl[4];
  const int w = t >> 6, lane = t & 63;
  if (lane == 0) { sm[w] = m; sl[w] = l; }
  __syncthreads();
  if (t == 0) {
    float M = sm[0], L = sl[0];
#pragma unroll
    for (int q = 1; q < 4; ++q) {
      const float mn = fmaxf(M, sm[q]);
      L = L*__expf(M - mn) + sl[q]*__expf(sm[q] - mn);
      M = mn;
    }
    pm2[blockIdx.x] = M; pl2[blockIdx.x] = L;
  }
}

// ---------------------------------------------------------------------------
// Kernel E2: logits -= c[row]; c computed per-block from the 8 partials.
// ---------------------------------------------------------------------------
__global__ __launch_bounds__(256) void lsm_sub(
    float* __restrict__ out, const float* __restrict__ pm2,
    const float* __restrict__ pl2)
{
  const int t = threadIdx.x;
  const size_t off = (size_t)blockIdx.x * 1024;
  const size_t total = (size_t)BB*VV;
  __shared__ float cs[2];
  __shared__ int rowA_s;
  if (t < 2) {
    size_t pos = (t == 0) ? off : (off + 1023 < total ? off + 1023 : total - 1);
    const int row = (int)(pos / VV);
    float M = -INFINITY, L = 0.f;
#pragma unroll
    for (int q = 0; q < LCH; ++q) {
      const float mq = pm2[row*LCH + q], lq = pl2[row*LCH + q];
      const float mn = fmaxf(M, mq);
      L = L*__expf(M - mn) + lq*__expf(mq - mn);
      M = mn;
    }
    cs[t] = M + logf(L);
    if (t == 0) rowA_s = row;
  }
  __syncthreads();

  const size_t i = off + (size_t)t*4;
  if (i >= total) return;
  const size_t rs = (size_t)(rowA_s + 1)*VV;   // start of next row
  float4 v = *(float4*)(out + i);
  v.x -= (i     >= rs) ? cs[1] : cs[0];
  v.y -= (i + 1 >= rs) ? cs[1] : cs[0];
  v.z -= (i + 2 >= rs) ? cs[1] : cs[0];
  v.w -= (i + 3 >= rs) ? cs[1] : cs[0];
  *(float4*)(out + i) = v;
}

// ---------------------------------------------------------------------------
extern "C" void kernel_launch(void* const* d_in, const int* in_sizes, int n_in,
                              void* d_out, int out_size, void* d_ws, size_t ws_size,
                              hipStream_t stream)
{
  const int*   last_output = (const int*)d_in[0];
  const float* last_hidden = (const float*)d_in[1];
  const float* enc         = (const float*)d_in[2];
  const float* emb         = (const float*)d_in[3];
  const float* W_ih        = (const float*)d_in[4];
  const float* b_ih        = (const float*)d_in[5];
  const float* W_hh        = (const float*)d_in[6];
  const float* b_hh        = (const float*)d_in[7];
  const float* W_out       = (const float*)d_in[8];
  const float* b_out       = (const float*)d_in[9];
  float* out = (float*)d_out;

  // ws layout
  __hip_bfloat16* featb = (__hip_bfloat16*)d_ws;                    // 64x1024 bf16 (128 KB)
  float* gates = (float*)((char*)d_ws + (size_t)BB*KD*2);           // 3x64x1536 f32 (1.18 MB)
  float* pm   = gates + (size_t)3*BB*1536;
  float* pl   = pm + BB*NSPLIT;
  float* pm2  = pl + BB*NSPLIT;
  float* pl2  = pm2 + BB*LCH;
  float* pacc = out;  // 4 MB parked in dead logits region

  float* logits  = out;
  float* hid_out = out + (size_t)BB*VV;

  attn_partial <<<dim3(BB*NSPLIT), dim3(256), 0, stream>>>(last_hidden, enc, pm, pl, pacc);
  attn_reduce  <<<dim3(BB),        dim3(256), 0, stream>>>(pm, pl, pacc, featb);
  gru_gemm     <<<dim3(24*3),      dim3(256), 0, stream>>>(last_output, emb, last_hidden,
                                                           featb, W_ih, W_hh, gates);
  gru_pointwise<<<dim3(BB),        dim3(512), 0, stream>>>(gates, last_hidden, b_ih, b_hh,
                                                           hid_out, featb);
  logits_gemm  <<<dim3((VV+63)/64), dim3(256), 0, stream>>>(featb, W_out, b_out, logits);
  lsm_partial  <<<dim3(BB*LCH),    dim3(256), 0, stream>>>(logits, pm2, pl2);
  lsm_sub      <<<dim3((int)(((size_t)BB*VV + 1023)/1024)), dim3(256), 0, stream>>>(logits, pm2, pl2);
}